// Round 2
// baseline (2258.065 us; speedup 1.0000x reference)
//
#include <hip/hip_runtime.h>

#define N_NODES 50000
#define N_EDGES 800000
#define DIN 256
#define DOUT 64
#define LN_EPS 1e-5f
#define SCAN_NB 196   // ceil(N_NODES/256)

// ---------------- degree count ----------------
__global__ void count_kernel(const int* __restrict__ ei, int* __restrict__ cnt) {
    int e = blockIdx.x * blockDim.x + threadIdx.x;
    if (e < N_EDGES) atomicAdd(&cnt[ei[N_EDGES + e]], 1);
}

// ---------------- parallel scan: per-block sums ----------------
__global__ __launch_bounds__(256) void blockred_kernel(const int* __restrict__ cnt,
                                                       int* __restrict__ bsum) {
    __shared__ int ws[4];
    int tid = threadIdx.x, lane = tid & 63, wv = tid >> 6;
    int i = blockIdx.x * 256 + tid;
    int s = (i < N_NODES) ? cnt[i] : 0;
    #pragma unroll
    for (int d = 1; d < 64; d <<= 1) s += __shfl_xor(s, d, 64);
    if (lane == 0) ws[wv] = s;
    __syncthreads();
    if (tid == 0) bsum[blockIdx.x] = ws[0] + ws[1] + ws[2] + ws[3];
}

// ---------------- parallel scan: scan the block sums (1 block) ----------------
__global__ __launch_bounds__(256) void scansum_kernel(const int* __restrict__ bsum,
                                                      int* __restrict__ bpre) {
    __shared__ int ws[4];
    int tid = threadIdx.x, lane = tid & 63, wv = tid >> 6;
    int v = (tid < SCAN_NB) ? bsum[tid] : 0;
    int s = v;
    #pragma unroll
    for (int d = 1; d < 64; d <<= 1) { int t = __shfl_up(s, d, 64); if (lane >= d) s += t; }
    if (lane == 63) ws[wv] = s;
    __syncthreads();
    int pre = 0;
    #pragma unroll
    for (int w = 0; w < 4; ++w) if (w < wv) pre += ws[w];
    if (tid < SCAN_NB) bpre[tid] = pre + s - v;   // exclusive
}

// ---------------- parallel scan: per-block scan + offs + dinv ----------------
__global__ __launch_bounds__(256) void scatterscan_kernel(const int* __restrict__ cnt,
        const int* __restrict__ bpre, int* __restrict__ offs, float* __restrict__ dinv) {
    __shared__ int ws[4];
    int tid = threadIdx.x, lane = tid & 63, wv = tid >> 6;
    int i = blockIdx.x * 256 + tid;
    int v = (i < N_NODES) ? cnt[i] : 0;
    int s = v;
    #pragma unroll
    for (int d = 1; d < 64; d <<= 1) { int t = __shfl_up(s, d, 64); if (lane >= d) s += t; }
    if (lane == 63) ws[wv] = s;
    __syncthreads();
    int pre = bpre[blockIdx.x];
    #pragma unroll
    for (int w = 0; w < 4; ++w) if (w < wv) pre += ws[w];
    if (i < N_NODES) {
        offs[i + 1] = pre + s;
        dinv[i] = rsqrtf((float)(v + 1));   // +1 self loop
    }
    if (i == 0) offs[0] = 0;
}

// ---------------- CSR fill ----------------
__global__ void fill_kernel(const int* __restrict__ ei, const int* __restrict__ offs,
                            int* __restrict__ cursor, int* __restrict__ csr) {
    int e = blockIdx.x * blockDim.x + threadIdx.x;
    if (e < N_EDGES) {
        int s = ei[e];
        int d = ei[N_EDGES + e];
        int pos = atomicAdd(&cursor[d], 1);
        csr[offs[d] + pos] = s;
    }
}

// ---------------- GEMM: h[n][d] = sum_k xs[n][k] * W[d][k] ----------------
// 4 waves/block, 8 rows/wave (32 rows/block); lane = output feature.
// W staged in K-chunks of 64 (16KB fp32 as float4[64][16]), double-buffered (32KB LDS)
// so occupancy is VGPR-limited (~16-20 waves/CU), not LDS-limited.
__global__ __launch_bounds__(256) void gemm_kernel(const float* __restrict__ xs,
                                                   const float* __restrict__ W,
                                                   float* __restrict__ h) {
    __shared__ float4 wl[2][64 * 16];
    const int tid = threadIdx.x;
    const int lane = tid & 63, wv = tid >> 6;
    const float4* w4 = (const float4*)W;    // [64][64] float4
    const float4* x4 = (const float4*)xs;   // [N][64] float4

    int n0 = blockIdx.x * 32 + wv * 8;
    size_t base[8];
    #pragma unroll
    for (int i = 0; i < 8; ++i) {
        int r = n0 + i; if (r > N_NODES - 1) r = N_NODES - 1;  // clamp for safe loads
        base[i] = (size_t)r * 64;
    }
    float acc[8] = {0, 0, 0, 0, 0, 0, 0, 0};

    // stage chunk 0
    #pragma unroll
    for (int i = 0; i < 4; ++i) {
        int j = tid + i * 256;
        int row = j >> 4, col = j & 15;
        wl[0][row * 16 + (col ^ (row & 15))] = w4[row * 64 + col];
    }
    __syncthreads();

    const int sw = lane & 15;
    #pragma unroll
    for (int c = 0; c < 4; ++c) {
        if (c < 3) {   // prefetch next chunk into the other buffer
            #pragma unroll
            for (int i = 0; i < 4; ++i) {
                int j = tid + i * 256;
                int row = j >> 4, col = j & 15;
                wl[(c + 1) & 1][row * 16 + (col ^ (row & 15))] =
                    w4[row * 64 + (c + 1) * 16 + col];
            }
        }
        const float4* wrow = wl[c & 1] + lane * 16;
        #pragma unroll
        for (int j = 0; j < 16; ++j) {
            float4 w_ = wrow[j ^ sw];
            int kk = c * 16 + j;
            #pragma unroll
            for (int i = 0; i < 8; ++i) {
                float4 a = x4[base[i] + kk];
                acc[i] += a.x * w_.x + a.y * w_.y + a.z * w_.z + a.w * w_.w;
            }
        }
        __syncthreads();
    }
    #pragma unroll
    for (int i = 0; i < 8; ++i) {
        int r = n0 + i;
        if (r < N_NODES) h[(size_t)r * DOUT + lane] = acc[i];
    }
}

// ---------------- gather + bias + LayerNorm ----------------
// one wave per node; lane = feature. node/start/end/csr/dinv indices are
// wave-uniform (readfirstlane) -> compiler scalarizes them to s_loads; no shfls.
__global__ __launch_bounds__(256) void gather_ln_kernel(
    const float* __restrict__ h, const int* __restrict__ offs, const int* __restrict__ csr,
    const float* __restrict__ dinv, const float* __restrict__ bias,
    const float* __restrict__ gamma, const float* __restrict__ beta,
    float* __restrict__ out) {
    int wv = __builtin_amdgcn_readfirstlane(threadIdx.x >> 6);
    int node = blockIdx.x * 4 + wv;
    if (node >= N_NODES) return;
    int lane = threadIdx.x & 63;
    int start = offs[node], end = offs[node + 1];
    float di = dinv[node];
    float acc = h[(size_t)node * DOUT + lane] * di;   // self loop
    int c = start;
    for (; c + 4 <= end; c += 4) {
        int s0 = csr[c], s1 = csr[c + 1], s2 = csr[c + 2], s3 = csr[c + 3];
        float w0 = dinv[s0], w1 = dinv[s1], w2 = dinv[s2], w3 = dinv[s3];
        float h0 = h[(size_t)s0 * DOUT + lane];
        float h1 = h[(size_t)s1 * DOUT + lane];
        float h2 = h[(size_t)s2 * DOUT + lane];
        float h3 = h[(size_t)s3 * DOUT + lane];
        acc = fmaf(h0, w0, acc);
        acc = fmaf(h1, w1, acc);
        acc = fmaf(h2, w2, acc);
        acc = fmaf(h3, w3, acc);
    }
    for (; c < end; ++c) {
        int s0 = csr[c];
        acc = fmaf(h[(size_t)s0 * DOUT + lane], dinv[s0], acc);
    }
    acc = acc * di + bias[lane];
    // LayerNorm over 64 features (one wave)
    float sum = acc;
    #pragma unroll
    for (int d = 1; d < 64; d <<= 1) sum += __shfl_xor(sum, d, 64);
    float mu = sum * (1.0f / 64.0f);
    float diff = acc - mu;
    float vs = diff * diff;
    #pragma unroll
    for (int d = 1; d < 64; d <<= 1) vs += __shfl_xor(vs, d, 64);
    float var = vs * (1.0f / 64.0f);
    float r = rsqrtf(var + LN_EPS);
    out[(size_t)node * DOUT + lane] = diff * r * gamma[lane] + beta[lane];
}

extern "C" void kernel_launch(void* const* d_in, const int* in_sizes, int n_in,
                              void* d_out, int out_size, void* d_ws, size_t ws_size,
                              hipStream_t stream) {
    const float* xs    = (const float*)d_in[0];
    const int*   ei    = (const int*)d_in[1];
    const float* W     = (const float*)d_in[2];
    const float* bias  = (const float*)d_in[3];
    const float* gamma = (const float*)d_in[4];
    const float* beta  = (const float*)d_in[5];
    float* out = (float*)d_out;

    char* base = (char*)d_ws;
    auto align_up = [](size_t x) { return (x + 255) & ~(size_t)255; };
    size_t o = 0;
    int* cnt    = (int*)(base + o);   o = align_up(o + (size_t)N_NODES * 4);
    int* cursor = (int*)(base + o);   o = align_up(o + (size_t)N_NODES * 4);
    size_t zero_bytes = o;            // cnt + cursor regions
    int* offs   = (int*)(base + o);   o = align_up(o + (size_t)(N_NODES + 1) * 4);
    float* dinv = (float*)(base + o); o = align_up(o + (size_t)N_NODES * 4);
    int* csr    = (int*)(base + o);   o = align_up(o + (size_t)N_EDGES * 4);
    float* h    = (float*)(base + o); o = align_up(o + (size_t)N_NODES * DOUT * 4);
    int* bsum   = (int*)(base + o);   o = align_up(o + (size_t)SCAN_NB * 4);
    int* bpre   = (int*)(base + o);   o = align_up(o + (size_t)SCAN_NB * 4);
    (void)ws_size; (void)in_sizes; (void)n_in; (void)out_size;

    hipMemsetAsync(d_ws, 0, zero_bytes, stream);
    count_kernel<<<(N_EDGES + 255) / 256, 256, 0, stream>>>(ei, cnt);
    gemm_kernel<<<(N_NODES + 31) / 32, 256, 0, stream>>>(xs, W, h);
    blockred_kernel<<<SCAN_NB, 256, 0, stream>>>(cnt, bsum);
    scansum_kernel<<<1, 256, 0, stream>>>(bsum, bpre);
    scatterscan_kernel<<<SCAN_NB, 256, 0, stream>>>(cnt, bpre, offs, dinv);
    fill_kernel<<<(N_EDGES + 255) / 256, 256, 0, stream>>>(ei, offs, cursor, csr);
    gather_ln_kernel<<<(N_NODES + 3) / 4, 256, 0, stream>>>(h, offs, csr, dinv,
                                                            bias, gamma, beta, out);
}

// Round 3
// 212.212 us; speedup vs baseline: 10.6406x; 10.6406x over previous
//
#include <hip/hip_runtime.h>

#define N_NODES 50000
#define N_EDGES 800000
#define DIN 256
#define DOUT 64
#define LN_EPS 1e-5f
#define SCAN_NB 196   // ceil(N_NODES/256)

// ---------------- degree count ----------------
__global__ void count_kernel(const int* __restrict__ ei, int* __restrict__ cnt) {
    int e = blockIdx.x * blockDim.x + threadIdx.x;
    if (e < N_EDGES) atomicAdd(&cnt[ei[N_EDGES + e]], 1);
}

// ---------------- parallel scan: per-block sums ----------------
__global__ __launch_bounds__(256) void blockred_kernel(const int* __restrict__ cnt,
                                                       int* __restrict__ bsum) {
    __shared__ int ws[4];
    int tid = threadIdx.x, lane = tid & 63, wv = tid >> 6;
    int i = blockIdx.x * 256 + tid;
    int s = (i < N_NODES) ? cnt[i] : 0;
    #pragma unroll
    for (int d = 1; d < 64; d <<= 1) s += __shfl_xor(s, d, 64);
    if (lane == 0) ws[wv] = s;
    __syncthreads();
    if (tid == 0) bsum[blockIdx.x] = ws[0] + ws[1] + ws[2] + ws[3];
}

// ---------------- parallel scan: scan the block sums (1 block) ----------------
__global__ __launch_bounds__(256) void scansum_kernel(const int* __restrict__ bsum,
                                                      int* __restrict__ bpre) {
    __shared__ int ws[4];
    int tid = threadIdx.x, lane = tid & 63, wv = tid >> 6;
    int v = (tid < SCAN_NB) ? bsum[tid] : 0;
    int s = v;
    #pragma unroll
    for (int d = 1; d < 64; d <<= 1) { int t = __shfl_up(s, d, 64); if (lane >= d) s += t; }
    if (lane == 63) ws[wv] = s;
    __syncthreads();
    int pre = 0;
    #pragma unroll
    for (int w = 0; w < 4; ++w) if (w < wv) pre += ws[w];
    if (tid < SCAN_NB) bpre[tid] = pre + s - v;   // exclusive
}

// ---------------- parallel scan: per-block scan + offs + dinv ----------------
__global__ __launch_bounds__(256) void scatterscan_kernel(const int* __restrict__ cnt,
        const int* __restrict__ bpre, int* __restrict__ offs, float* __restrict__ dinv) {
    __shared__ int ws[4];
    int tid = threadIdx.x, lane = tid & 63, wv = tid >> 6;
    int i = blockIdx.x * 256 + tid;
    int v = (i < N_NODES) ? cnt[i] : 0;
    int s = v;
    #pragma unroll
    for (int d = 1; d < 64; d <<= 1) { int t = __shfl_up(s, d, 64); if (lane >= d) s += t; }
    if (lane == 63) ws[wv] = s;
    __syncthreads();
    int pre = bpre[blockIdx.x];
    #pragma unroll
    for (int w = 0; w < 4; ++w) if (w < wv) pre += ws[w];
    if (i < N_NODES) {
        offs[i + 1] = pre + s;
        dinv[i] = rsqrtf((float)(v + 1));   // +1 self loop
    }
    if (i == 0) offs[0] = 0;
}

// ---------------- CSR fill ----------------
__global__ void fill_kernel(const int* __restrict__ ei, const int* __restrict__ offs,
                            int* __restrict__ cursor, int* __restrict__ csr) {
    int e = blockIdx.x * blockDim.x + threadIdx.x;
    if (e < N_EDGES) {
        int s = ei[e];
        int d = ei[N_EDGES + e];
        int pos = atomicAdd(&cursor[d], 1);
        csr[offs[d] + pos] = s;
    }
}

// ---------------- GEMM: h[n][d] = sum_k xs[n][k] * W[d][k] ----------------
// 512 threads = 8 waves; lane = output feature; 8 rows/wave, 64 rows/block.
// Full W (64KB) staged in LDS once. Swizzle: float4 col' = (col&48)|((col^row)&15)
// -> each 8-lane cycle group of a b128 read hits 8 distinct bank quads.
// xs row addresses are wave-uniform (readfirstlane) -> scalar loads.
// __launch_bounds__(512,4): cap VGPR<=128 so 2 blocks/CU (16 waves/CU).
__global__ __launch_bounds__(512, 4) void gemm_kernel(const float* __restrict__ xs,
                                                      const float* __restrict__ W,
                                                      float* __restrict__ h) {
    __shared__ float4 wl[64 * 64];   // 64KB
    const int tid = threadIdx.x;
    const float4* w4 = (const float4*)W;
    #pragma unroll
    for (int i = 0; i < 8; ++i) {
        int j = tid + i * 512;               // 0..4095
        int row = j >> 6, col = j & 63;
        int colp = (col & 48) | ((col ^ row) & 15);
        wl[row * 64 + colp] = w4[j];
    }
    __syncthreads();

    const int lane = tid & 63, wv = tid >> 6;
    const int n0 = blockIdx.x * 64 + wv * 8;
    const float4* xr0;
    const float4* xr1;
    const float4* xr2;
    const float4* xr3;
    const float4* xr4;
    const float4* xr5;
    const float4* xr6;
    const float4* xr7;
    {
        int r0 = n0 + 0; if (r0 >= N_NODES) r0 = N_NODES - 1;
        int r1 = n0 + 1; if (r1 >= N_NODES) r1 = N_NODES - 1;
        int r2 = n0 + 2; if (r2 >= N_NODES) r2 = N_NODES - 1;
        int r3 = n0 + 3; if (r3 >= N_NODES) r3 = N_NODES - 1;
        int r4 = n0 + 4; if (r4 >= N_NODES) r4 = N_NODES - 1;
        int r5 = n0 + 5; if (r5 >= N_NODES) r5 = N_NODES - 1;
        int r6 = n0 + 6; if (r6 >= N_NODES) r6 = N_NODES - 1;
        int r7 = n0 + 7; if (r7 >= N_NODES) r7 = N_NODES - 1;
        xr0 = (const float4*)(xs + (size_t)__builtin_amdgcn_readfirstlane(r0) * DIN);
        xr1 = (const float4*)(xs + (size_t)__builtin_amdgcn_readfirstlane(r1) * DIN);
        xr2 = (const float4*)(xs + (size_t)__builtin_amdgcn_readfirstlane(r2) * DIN);
        xr3 = (const float4*)(xs + (size_t)__builtin_amdgcn_readfirstlane(r3) * DIN);
        xr4 = (const float4*)(xs + (size_t)__builtin_amdgcn_readfirstlane(r4) * DIN);
        xr5 = (const float4*)(xs + (size_t)__builtin_amdgcn_readfirstlane(r5) * DIN);
        xr6 = (const float4*)(xs + (size_t)__builtin_amdgcn_readfirstlane(r6) * DIN);
        xr7 = (const float4*)(xs + (size_t)__builtin_amdgcn_readfirstlane(r7) * DIN);
    }
    float a0 = 0.f, a1 = 0.f, a2 = 0.f, a3 = 0.f;
    float a4 = 0.f, a5 = 0.f, a6 = 0.f, a7 = 0.f;
    const float4* wrow = wl + lane * 64;
    #pragma unroll 2
    for (int k = 0; k < 64; ++k) {
        float4 w_ = wrow[(k & 48) | ((k ^ lane) & 15)];
        float4 x0 = xr0[k];
        float4 x1 = xr1[k];
        float4 x2 = xr2[k];
        float4 x3 = xr3[k];
        a0 += x0.x * w_.x + x0.y * w_.y + x0.z * w_.z + x0.w * w_.w;
        a1 += x1.x * w_.x + x1.y * w_.y + x1.z * w_.z + x1.w * w_.w;
        a2 += x2.x * w_.x + x2.y * w_.y + x2.z * w_.z + x2.w * w_.w;
        a3 += x3.x * w_.x + x3.y * w_.y + x3.z * w_.z + x3.w * w_.w;
        float4 x4 = xr4[k];
        float4 x5 = xr5[k];
        float4 x6 = xr6[k];
        float4 x7 = xr7[k];
        a4 += x4.x * w_.x + x4.y * w_.y + x4.z * w_.z + x4.w * w_.w;
        a5 += x5.x * w_.x + x5.y * w_.y + x5.z * w_.z + x5.w * w_.w;
        a6 += x6.x * w_.x + x6.y * w_.y + x6.z * w_.z + x6.w * w_.w;
        a7 += x7.x * w_.x + x7.y * w_.y + x7.z * w_.z + x7.w * w_.w;
    }
    float acc[8] = {a0, a1, a2, a3, a4, a5, a6, a7};
    #pragma unroll
    for (int i = 0; i < 8; ++i) {
        int r = n0 + i;
        if (r < N_NODES) h[(size_t)r * DOUT + lane] = acc[i];
    }
}

// ---------------- gather + bias + LayerNorm ----------------
// one wave per node; lane = feature. CSR/dinv indices are wave-uniform -> s_loads.
__global__ __launch_bounds__(256) void gather_ln_kernel(
    const float* __restrict__ h, const int* __restrict__ offs, const int* __restrict__ csr,
    const float* __restrict__ dinv, const float* __restrict__ bias,
    const float* __restrict__ gamma, const float* __restrict__ beta,
    float* __restrict__ out) {
    int wv = __builtin_amdgcn_readfirstlane(threadIdx.x >> 6);
    int node = blockIdx.x * 4 + wv;
    if (node >= N_NODES) return;
    int lane = threadIdx.x & 63;
    int start = offs[node], end = offs[node + 1];
    float di = dinv[node];
    float acc = h[(size_t)node * DOUT + lane] * di;   // self loop
    int c = start;
    for (; c + 4 <= end; c += 4) {
        int s0 = csr[c], s1 = csr[c + 1], s2 = csr[c + 2], s3 = csr[c + 3];
        float w0 = dinv[s0], w1 = dinv[s1], w2 = dinv[s2], w3 = dinv[s3];
        float h0 = h[(size_t)s0 * DOUT + lane];
        float h1 = h[(size_t)s1 * DOUT + lane];
        float h2 = h[(size_t)s2 * DOUT + lane];
        float h3 = h[(size_t)s3 * DOUT + lane];
        acc = fmaf(h0, w0, acc);
        acc = fmaf(h1, w1, acc);
        acc = fmaf(h2, w2, acc);
        acc = fmaf(h3, w3, acc);
    }
    for (; c < end; ++c) {
        int s0 = csr[c];
        acc = fmaf(h[(size_t)s0 * DOUT + lane], dinv[s0], acc);
    }
    acc = acc * di + bias[lane];
    // LayerNorm over 64 features (one wave)
    float sum = acc;
    #pragma unroll
    for (int d = 1; d < 64; d <<= 1) sum += __shfl_xor(sum, d, 64);
    float mu = sum * (1.0f / 64.0f);
    float diff = acc - mu;
    float vs = diff * diff;
    #pragma unroll
    for (int d = 1; d < 64; d <<= 1) vs += __shfl_xor(vs, d, 64);
    float var = vs * (1.0f / 64.0f);
    float r = rsqrtf(var + LN_EPS);
    out[(size_t)node * DOUT + lane] = diff * r * gamma[lane] + beta[lane];
}

extern "C" void kernel_launch(void* const* d_in, const int* in_sizes, int n_in,
                              void* d_out, int out_size, void* d_ws, size_t ws_size,
                              hipStream_t stream) {
    const float* xs    = (const float*)d_in[0];
    const int*   ei    = (const int*)d_in[1];
    const float* W     = (const float*)d_in[2];
    const float* bias  = (const float*)d_in[3];
    const float* gamma = (const float*)d_in[4];
    const float* beta  = (const float*)d_in[5];
    float* out = (float*)d_out;

    char* base = (char*)d_ws;
    auto align_up = [](size_t x) { return (x + 255) & ~(size_t)255; };
    size_t o = 0;
    int* cnt    = (int*)(base + o);   o = align_up(o + (size_t)N_NODES * 4);
    int* cursor = (int*)(base + o);   o = align_up(o + (size_t)N_NODES * 4);
    size_t zero_bytes = o;            // cnt + cursor regions
    int* offs   = (int*)(base + o);   o = align_up(o + (size_t)(N_NODES + 1) * 4);
    float* dinv = (float*)(base + o); o = align_up(o + (size_t)N_NODES * 4);
    int* csr    = (int*)(base + o);   o = align_up(o + (size_t)N_EDGES * 4);
    float* h    = (float*)(base + o); o = align_up(o + (size_t)N_NODES * DOUT * 4);
    int* bsum   = (int*)(base + o);   o = align_up(o + (size_t)SCAN_NB * 4);
    int* bpre   = (int*)(base + o);   o = align_up(o + (size_t)SCAN_NB * 4);
    (void)ws_size; (void)in_sizes; (void)n_in; (void)out_size;

    hipMemsetAsync(d_ws, 0, zero_bytes, stream);
    count_kernel<<<(N_EDGES + 255) / 256, 256, 0, stream>>>(ei, cnt);
    gemm_kernel<<<(N_NODES + 63) / 64, 512, 0, stream>>>(xs, W, h);
    blockred_kernel<<<SCAN_NB, 256, 0, stream>>>(cnt, bsum);
    scansum_kernel<<<1, 256, 0, stream>>>(bsum, bpre);
    scatterscan_kernel<<<SCAN_NB, 256, 0, stream>>>(cnt, bpre, offs, dinv);
    fill_kernel<<<(N_EDGES + 255) / 256, 256, 0, stream>>>(ei, offs, cursor, csr);
    gather_ln_kernel<<<(N_NODES + 3) / 4, 256, 0, stream>>>(h, offs, csr, dinv,
                                                            bias, gamma, beta, out);
}

// Round 4
// 137.353 us; speedup vs baseline: 16.4399x; 1.5450x over previous
//
#include <hip/hip_runtime.h>

#define N_NODES 50000
#define N_EDGES 800000
#define DIN 256
#define DOUT 64
#define LN_EPS 1e-5f
#define SCAN_NB 196   // ceil(N_NODES/256)

typedef __attribute__((ext_vector_type(8))) short bfrag8;
typedef __attribute__((ext_vector_type(4))) float f32x4;

__device__ inline unsigned short f2bf(float f) {
    unsigned u = __builtin_bit_cast(unsigned, f);
    u += 0x7fffu + ((u >> 16) & 1u);          // round-to-nearest-even
    return (unsigned short)(u >> 16);
}
__device__ inline float bf2f(unsigned short b) {
    unsigned u = ((unsigned)b) << 16;
    return __builtin_bit_cast(float, u);
}

// ---------------- degree count ----------------
__global__ void count_kernel(const int* __restrict__ ei, int* __restrict__ cnt) {
    int e = blockIdx.x * blockDim.x + threadIdx.x;
    if (e < N_EDGES) atomicAdd(&cnt[ei[N_EDGES + e]], 1);
}

// ---------------- parallel scan: per-block sums ----------------
__global__ __launch_bounds__(256) void blockred_kernel(const int* __restrict__ cnt,
                                                       int* __restrict__ bsum) {
    __shared__ int ws[4];
    int tid = threadIdx.x, lane = tid & 63, wv = tid >> 6;
    int i = blockIdx.x * 256 + tid;
    int s = (i < N_NODES) ? cnt[i] : 0;
    #pragma unroll
    for (int d = 1; d < 64; d <<= 1) s += __shfl_xor(s, d, 64);
    if (lane == 0) ws[wv] = s;
    __syncthreads();
    if (tid == 0) bsum[blockIdx.x] = ws[0] + ws[1] + ws[2] + ws[3];
}

// ---------------- parallel scan: scan the block sums (1 block) ----------------
__global__ __launch_bounds__(256) void scansum_kernel(const int* __restrict__ bsum,
                                                      int* __restrict__ bpre) {
    __shared__ int ws[4];
    int tid = threadIdx.x, lane = tid & 63, wv = tid >> 6;
    int v = (tid < SCAN_NB) ? bsum[tid] : 0;
    int s = v;
    #pragma unroll
    for (int d = 1; d < 64; d <<= 1) { int t = __shfl_up(s, d, 64); if (lane >= d) s += t; }
    if (lane == 63) ws[wv] = s;
    __syncthreads();
    int pre = 0;
    #pragma unroll
    for (int w = 0; w < 4; ++w) if (w < wv) pre += ws[w];
    if (tid < SCAN_NB) bpre[tid] = pre + s - v;   // exclusive
}

// ---------------- parallel scan: per-block scan + offs + dinv ----------------
__global__ __launch_bounds__(256) void scatterscan_kernel(const int* __restrict__ cnt,
        const int* __restrict__ bpre, int* __restrict__ offs, float* __restrict__ dinv) {
    __shared__ int ws[4];
    int tid = threadIdx.x, lane = tid & 63, wv = tid >> 6;
    int i = blockIdx.x * 256 + tid;
    int v = (i < N_NODES) ? cnt[i] : 0;
    int s = v;
    #pragma unroll
    for (int d = 1; d < 64; d <<= 1) { int t = __shfl_up(s, d, 64); if (lane >= d) s += t; }
    if (lane == 63) ws[wv] = s;
    __syncthreads();
    int pre = bpre[blockIdx.x];
    #pragma unroll
    for (int w = 0; w < 4; ++w) if (w < wv) pre += ws[w];
    if (i < N_NODES) {
        offs[i + 1] = pre + s;
        dinv[i] = rsqrtf((float)(v + 1));   // +1 self loop
    }
    if (i == 0) offs[0] = 0;
}

// ---------------- CSR fill ----------------
__global__ void fill_kernel(const int* __restrict__ ei, const int* __restrict__ offs,
                            int* __restrict__ cursor, int* __restrict__ csr) {
    int e = blockIdx.x * blockDim.x + threadIdx.x;
    if (e < N_EDGES) {
        int s = ei[e];
        int d = ei[N_EDGES + e];
        int pos = atomicAdd(&cursor[d], 1);
        csr[offs[d] + pos] = s;
    }
}

// ---------------- MFMA GEMM: h[n][d] = sum_k xs[n][k] * W[d][k], h in bf16 ----
// 256 threads = 4 waves; wave computes 16 rows x 64 cols via 4 N-tiles of
// mfma_f32_16x16x32_bf16, K-loop 8 steps of 32.
// W staged once/block into LDS as bf16 [64 rows][32 groups of 8], group-XOR
// swizzled (g ^= row&7) -> B-frag ds_read_b128 is 2-way at worst (free).
// A loaded straight from global: lane l -> row n0+(l&15), k-chunk (l>>4)*8;
// 4 lanes cover one contiguous 128B row segment (coalesced), fp32->bf16 inline.
__global__ __launch_bounds__(256) void gemm_kernel(const float* __restrict__ xs,
                                                   const float* __restrict__ W,
                                                   unsigned short* __restrict__ h) {
    __shared__ bfrag8 wg[64 * 32];   // 32KB bf16 W
    const int tid = threadIdx.x;
    // stage W: 2048 groups of 8 floats; 8 per thread
    #pragma unroll
    for (int i = 0; i < 8; ++i) {
        int gi = tid + i * 256;              // 0..2047
        int d = gi >> 5, g = gi & 31;
        const float* src = W + d * 256 + g * 8;
        f32x4 f0 = *(const f32x4*)src;
        f32x4 f1 = *(const f32x4*)(src + 4);
        union { unsigned short us[8]; bfrag8 v; } p;
        p.us[0] = f2bf(f0.x); p.us[1] = f2bf(f0.y);
        p.us[2] = f2bf(f0.z); p.us[3] = f2bf(f0.w);
        p.us[4] = f2bf(f1.x); p.us[5] = f2bf(f1.y);
        p.us[6] = f2bf(f1.z); p.us[7] = f2bf(f1.w);
        wg[d * 32 + (g ^ (d & 7))] = p.v;
    }
    __syncthreads();

    const int lane = tid & 63, wv = tid >> 6;
    const int n0 = (blockIdx.x * 4 + wv) * 16;
    int arow = n0 + (lane & 15);
    if (arow >= N_NODES) arow = N_NODES - 1;          // clamp (loads only)
    const float* xrow = xs + (size_t)arow * DIN + (lane >> 4) * 8;

    f32x4 acc[4] = {{0.f, 0.f, 0.f, 0.f}, {0.f, 0.f, 0.f, 0.f},
                    {0.f, 0.f, 0.f, 0.f}, {0.f, 0.f, 0.f, 0.f}};
    const int swz = lane & 7;       // (t*16 + (lane&15)) & 7 == lane & 7
    #pragma unroll
    for (int s = 0; s < 8; ++s) {
        f32x4 xa = *(const f32x4*)(xrow + s * 32);
        f32x4 xb = *(const f32x4*)(xrow + s * 32 + 4);
        union { unsigned short us[8]; bfrag8 v; } a;
        a.us[0] = f2bf(xa.x); a.us[1] = f2bf(xa.y);
        a.us[2] = f2bf(xa.z); a.us[3] = f2bf(xa.w);
        a.us[4] = f2bf(xb.x); a.us[5] = f2bf(xb.y);
        a.us[6] = f2bf(xb.z); a.us[7] = f2bf(xb.w);
        int g = s * 4 + (lane >> 4);
        #pragma unroll
        for (int t = 0; t < 4; ++t) {
            bfrag8 b = wg[(t * 16 + (lane & 15)) * 32 + (g ^ swz)];
            acc[t] = __builtin_amdgcn_mfma_f32_16x16x32_bf16(a.v, b, acc[t], 0, 0, 0);
        }
    }
    // C/D: col = lane&15, row = (lane>>4)*4 + r   [m89-verified]
    #pragma unroll
    for (int t = 0; t < 4; ++t) {
        #pragma unroll
        for (int r = 0; r < 4; ++r) {
            int row = n0 + (lane >> 4) * 4 + r;
            if (row < N_NODES)
                h[(size_t)row * DOUT + t * 16 + (lane & 15)] = f2bf(acc[t][r]);
        }
    }
}

// ---------------- gather + bias + LayerNorm ----------------
// one wave per node; lane = feature; h is bf16 (half the random-read bytes).
__global__ __launch_bounds__(256) void gather_ln_kernel(
    const unsigned short* __restrict__ h, const int* __restrict__ offs,
    const int* __restrict__ csr, const float* __restrict__ dinv,
    const float* __restrict__ bias, const float* __restrict__ gamma,
    const float* __restrict__ beta, float* __restrict__ out) {
    int wv = __builtin_amdgcn_readfirstlane(threadIdx.x >> 6);
    int node = blockIdx.x * 4 + wv;
    if (node >= N_NODES) return;
    int lane = threadIdx.x & 63;
    int start = offs[node], end = offs[node + 1];
    float di = dinv[node];
    float acc = bf2f(h[(size_t)node * DOUT + lane]) * di;   // self loop
    int c = start;
    for (; c + 4 <= end; c += 4) {
        int s0 = csr[c], s1 = csr[c + 1], s2 = csr[c + 2], s3 = csr[c + 3];
        float w0 = dinv[s0], w1 = dinv[s1], w2 = dinv[s2], w3 = dinv[s3];
        float h0 = bf2f(h[(size_t)s0 * DOUT + lane]);
        float h1 = bf2f(h[(size_t)s1 * DOUT + lane]);
        float h2 = bf2f(h[(size_t)s2 * DOUT + lane]);
        float h3 = bf2f(h[(size_t)s3 * DOUT + lane]);
        acc = fmaf(h0, w0, acc);
        acc = fmaf(h1, w1, acc);
        acc = fmaf(h2, w2, acc);
        acc = fmaf(h3, w3, acc);
    }
    for (; c < end; ++c) {
        int s0 = csr[c];
        acc = fmaf(bf2f(h[(size_t)s0 * DOUT + lane]), dinv[s0], acc);
    }
    acc = acc * di + bias[lane];
    // LayerNorm over 64 features (one wave)
    float sum = acc;
    #pragma unroll
    for (int d = 1; d < 64; d <<= 1) sum += __shfl_xor(sum, d, 64);
    float mu = sum * (1.0f / 64.0f);
    float diff = acc - mu;
    float vs = diff * diff;
    #pragma unroll
    for (int d = 1; d < 64; d <<= 1) vs += __shfl_xor(vs, d, 64);
    float var = vs * (1.0f / 64.0f);
    float r = rsqrtf(var + LN_EPS);
    out[(size_t)node * DOUT + lane] = diff * r * gamma[lane] + beta[lane];
}

extern "C" void kernel_launch(void* const* d_in, const int* in_sizes, int n_in,
                              void* d_out, int out_size, void* d_ws, size_t ws_size,
                              hipStream_t stream) {
    const float* xs    = (const float*)d_in[0];
    const int*   ei    = (const int*)d_in[1];
    const float* W     = (const float*)d_in[2];
    const float* bias  = (const float*)d_in[3];
    const float* gamma = (const float*)d_in[4];
    const float* beta  = (const float*)d_in[5];
    float* out = (float*)d_out;

    char* base = (char*)d_ws;
    auto align_up = [](size_t x) { return (x + 255) & ~(size_t)255; };
    size_t o = 0;
    int* cnt    = (int*)(base + o);   o = align_up(o + (size_t)N_NODES * 4);
    int* cursor = (int*)(base + o);   o = align_up(o + (size_t)N_NODES * 4);
    size_t zero_bytes = o;            // cnt + cursor regions
    int* offs   = (int*)(base + o);   o = align_up(o + (size_t)(N_NODES + 1) * 4);
    float* dinv = (float*)(base + o); o = align_up(o + (size_t)N_NODES * 4);
    int* csr    = (int*)(base + o);   o = align_up(o + (size_t)N_EDGES * 4);
    unsigned short* h = (unsigned short*)(base + o);
    o = align_up(o + (size_t)N_NODES * DOUT * 2);
    int* bsum   = (int*)(base + o);   o = align_up(o + (size_t)SCAN_NB * 4);
    int* bpre   = (int*)(base + o);   o = align_up(o + (size_t)SCAN_NB * 4);
    (void)ws_size; (void)in_sizes; (void)n_in; (void)out_size;

    hipMemsetAsync(d_ws, 0, zero_bytes, stream);
    count_kernel<<<(N_EDGES + 255) / 256, 256, 0, stream>>>(ei, cnt);
    gemm_kernel<<<(N_NODES + 63) / 64, 256, 0, stream>>>(xs, W, h);
    blockred_kernel<<<SCAN_NB, 256, 0, stream>>>(cnt, bsum);
    scansum_kernel<<<1, 256, 0, stream>>>(bsum, bpre);
    scatterscan_kernel<<<SCAN_NB, 256, 0, stream>>>(cnt, bpre, offs, dinv);
    fill_kernel<<<(N_EDGES + 255) / 256, 256, 0, stream>>>(ei, offs, cursor, csr);
    gather_ln_kernel<<<(N_NODES + 3) / 4, 256, 0, stream>>>(h, offs, csr, dinv,
                                                            bias, gamma, beta, out);
}